// Round 9
// baseline (2423.184 us; speedup 1.0000x reference)
//
#include <hip/hip_runtime.h>
#include <hip/hip_bf16.h>
#include <math.h>

#define B_ 16
#define S_ 512
#define E_ 300
#define H_ 512
#define V_ 10000
#define BS_ (B_ * S_)  // 8192

#define NSL 16           // slices per batch-pair (j-split)
#define JPB (H_ / NSL)   // 32 output rows per block
#define NBLK (8 * NSL)   // 128 blocks: pair p = blk&7 -> batches p, p+8

typedef __attribute__((ext_vector_type(4))) float f32x4;
typedef __attribute__((ext_vector_type(8))) short bf16x8;
typedef unsigned long long u64;

// ---------------------------------------------------------------------------
// K0: invalidate exchange tags in BOTH mailboxes (fast sc0 + safe sc1).
// ---------------------------------------------------------------------------
__global__ __launch_bounds__(256) void k0_init(u64* __restrict__ part) {
  const int idx = blockIdx.x * 256 + threadIdx.x;
  part[idx] = 0xFFFFFFFF00000000ull;
}

// ---------------------------------------------------------------------------
// K1: xw[bs,h] = sum_e x[bs,e] * W_ih[h,e] + b_ih[h] + b_hh[h]
// ---------------------------------------------------------------------------
__global__ __launch_bounds__(256) void k1_xw(const float* __restrict__ x,
                                             const float* __restrict__ W_ih,
                                             const float* __restrict__ b_ih,
                                             const float* __restrict__ b_hh,
                                             float* __restrict__ xw) {
  __shared__ float As[16][301];
  __shared__ float Ws[16][301];
  const int row0 = blockIdx.x * 16;
  const int col0 = blockIdx.y * 16;
  const int tid = threadIdx.x;
  for (int idx = tid; idx < 16 * E_; idx += 256) {
    int r = idx / E_, c = idx - r * E_;
    As[r][c] = x[(size_t)(row0 + r) * E_ + c];
    Ws[r][c] = W_ih[(size_t)(col0 + r) * E_ + c];
  }
  __syncthreads();
  const int i = tid >> 4, j = tid & 15;
  float acc = 0.f;
#pragma unroll 4
  for (int e = 0; e < E_; ++e) acc += As[i][e] * Ws[j][e];
  const int h = col0 + j;
  xw[(size_t)(row0 + i) * H_ + h] = acc + b_ih[h] + b_hh[h];
}

// sc1 (MALL-coherent) relaxed atomic load — always-correct path
__device__ __forceinline__ u64 pload(const u64* p) {
  return __hip_atomic_load(p, __ATOMIC_RELAXED, __HIP_MEMORY_SCOPE_AGENT);
}
// sc0 (L1-bypass, L2-point) dual load: 2 loads in flight, ONE vmcnt drain
__device__ __forceinline__ void load2_sc0(const u64* p0, const u64* p1,
                                          u64& r0, u64& r1) {
  asm volatile(
      "global_load_dwordx2 %0, %2, off sc0\n\t"
      "global_load_dwordx2 %1, %3, off sc0\n\t"
      "s_waitcnt vmcnt(0)"
      : "=&v"(r0), "=&v"(r1) : "v"(p0), "v"(p1) : "memory");
}
__device__ __forceinline__ void store_sc0(u64* p, u64 v) {
  asm volatile("global_store_dwordx2 %0, %1, off sc0" :: "v"(p), "v"(v)
               : "memory");
}

// ---------------------------------------------------------------------------
// K2: scan, j-split, LDS-resident W, XCD-local exchange, TWO batches per
// block (independent recurrence chains pipelined through one sync RT).
// Block (p = blk&7, g = blk>>3): batches b0=p, b1=p+8, rows [g*32,g*32+32).
// XCD-locality: blk%8 == p for all 16 slices of the pair (m09 round-robin).
// One W LDS tile (64 KB) serves both batches: per i4, 1 W read feeds 2 fmas.
// Publish: q==0 writes tagged u64 (t<<32|f32(h)) to fast (sc0/L2) + safe
// (sc1/MALL) mailboxes. Poll: each thread polls its word for BOTH batches
// with one dual-load (1 RT); 64-miss sticky downgrade per batch to the safe
// word keeps correctness under any dispatch placement.
// ---------------------------------------------------------------------------
__global__ __launch_bounds__(512) void k2_scan(
    const float* __restrict__ xw, const float* __restrict__ W_hh,
    float* __restrict__ hs, u64* __restrict__ part) {
  const int b0 = blockIdx.x & 7;
  const int b1 = b0 + 8;
  const int g = blockIdx.x >> 3;
  const int tid = threadIdx.x;
  const int j = tid >> 4;         // 0..31 row within slice
  const int q = tid & 15;         // k-sixteenth
  const int jg = g * JPB + j;     // global output row

  __shared__ f32x4 Wp[8 * 512];      // 64 KB, instruction-major W
  __shared__ f32x4 hp4[2][2][128];   // [slot][batch] h, i4-major

  {
    const float* wrow = &W_hh[(size_t)jg * H_ + q * 32];
#pragma unroll
    for (int i4 = 0; i4 < 8; ++i4)
      Wp[i4 * 512 + tid] = *(const f32x4*)&wrow[i4 * 4];
  }
  if (tid < 256) hp4[0][tid >> 7][tid & 127] = (f32x4)0.f;

  u64* const pf0 = part + (size_t)b0 * H_;
  u64* const pf1 = part + (size_t)b1 * H_;
  u64* const ps0 = part + (size_t)2 * B_ * H_ + (size_t)b0 * H_;
  u64* const ps1 = part + (size_t)2 * B_ * H_ + (size_t)b1 * H_;
  // poll word: thread tid fills float index tid of hp4[.][batch] =>
  // (i4=tid>>6, q=(tid>>2)&15, e=tid&3) => k = q*32 + i4*4 + e
  const int kk = ((tid >> 2) & 15) * 32 + (tid >> 6) * 4 + (tid & 3);
  bool fast0 = true, fast1 = true;

  float xwv0 = xw[(size_t)b0 * S_ * H_ + jg];
  float xwv1 = xw[(size_t)b1 * S_ * H_ + jg];
  __syncthreads();

  for (int t = 0; t < S_; ++t) {
    const int cur = t & 1;
    f32x4 a0 = (f32x4)0.f, a1 = (f32x4)0.f;
#pragma unroll
    for (int i4 = 0; i4 < 8; ++i4) {
      const f32x4 wv = Wp[i4 * 512 + tid];
      a0 += wv * hp4[cur][0][i4 * 16 + q];
      a1 += wv * hp4[cur][1][i4 * 16 + q];
    }
    float acc0 = a0.x + a0.y + a0.z + a0.w;
    float acc1 = a1.x + a1.y + a1.z + a1.w;
#pragma unroll
    for (int d = 1; d <= 8; d <<= 1) {
      acc0 += __shfl_xor(acc0, d);
      acc1 += __shfl_xor(acc1, d);
    }

    if (q == 0) {
      const float hn0 = tanhf(xwv0 + acc0);
      const float hn1 = tanhf(xwv1 + acc1);
      const u64 pk0 = ((u64)(unsigned)t << 32) | (unsigned)__float_as_uint(hn0);
      const u64 pk1 = ((u64)(unsigned)t << 32) | (unsigned)__float_as_uint(hn1);
      store_sc0(&pf0[(size_t)cur * (B_ * H_) + jg], pk0);
      store_sc0(&pf1[(size_t)cur * (B_ * H_) + jg], pk1);
      __hip_atomic_store(&ps0[(size_t)cur * (B_ * H_) + jg], pk0,
                         __ATOMIC_RELAXED, __HIP_MEMORY_SCOPE_AGENT);
      __hip_atomic_store(&ps1[(size_t)cur * (B_ * H_) + jg], pk1,
                         __ATOMIC_RELAXED, __HIP_MEMORY_SCOPE_AGENT);
      hs[((size_t)b0 * S_ + t) * H_ + jg] = hn0;
      hs[((size_t)b1 * S_ + t) * H_ + jg] = hn1;
    }
    const int tn = (t + 1 < S_) ? t + 1 : t;
    const float xwn0 = xw[((size_t)b0 * S_ + tn) * H_ + jg];
    const float xwn1 = xw[((size_t)b1 * S_ + tn) * H_ + jg];

    if (t + 1 < S_) {
      const unsigned ut = (unsigned)t;
      u64 v0 = 0, v1 = 0;
      bool g0 = false, g1 = false;
      const u64* f0 = &pf0[(size_t)cur * (B_ * H_) + kk];
      const u64* f1 = &pf1[(size_t)cur * (B_ * H_) + kk];
      if (fast0 | fast1) {
        for (int it = 0; it < 64; ++it) {
          u64 t0, t1;
          load2_sc0(f0, f1, t0, t1);
          if (!g0 && (unsigned)(t0 >> 32) == ut) { v0 = t0; g0 = true; }
          if (!g1 && (unsigned)(t1 >> 32) == ut) { v1 = t1; g1 = true; }
          if ((g0 | !fast0) & (g1 | !fast1)) break;
        }
        if (!g0) fast0 = false;
        if (!g1) fast1 = false;
      }
      if (!g0) {
        const u64* s0 = &ps0[(size_t)cur * (B_ * H_) + kk];
        v0 = pload(s0);
        while ((unsigned)(v0 >> 32) != ut) v0 = pload(s0);
      }
      if (!g1) {
        const u64* s1 = &ps1[(size_t)cur * (B_ * H_) + kk];
        v1 = pload(s1);
        while ((unsigned)(v1 >> 32) != ut) v1 = pload(s1);
      }
      ((float*)&hp4[cur ^ 1][0][0])[tid] = __uint_as_float((unsigned)v0);
      ((float*)&hp4[cur ^ 1][1][0])[tid] = __uint_as_float((unsigned)v1);
    }
    xwv0 = xwn0;
    xwv1 = xwn1;
    __syncthreads();
  }
}

// ---------------------------------------------------------------------------
// K5: split f32 -> bf16 hi + bf16 lo (RTN both; lo = f - hi).
// ---------------------------------------------------------------------------
__device__ __forceinline__ unsigned short bf16_rtn(float f) {
  unsigned u = __float_as_uint(f);
  return (unsigned short)((u + 0x7FFFu + ((u >> 16) & 1u)) >> 16);
}
__global__ __launch_bounds__(256) void k5_split(const float* __restrict__ src,
                                                unsigned short* __restrict__ hi,
                                                unsigned short* __restrict__ lo,
                                                int n4) {
  const int i = blockIdx.x * 256 + threadIdx.x;
  if (i >= n4) return;
  const float4 f = *(const float4*)&src[i * 4];
  unsigned short h[4], l[4];
  const float ff[4] = {f.x, f.y, f.z, f.w};
#pragma unroll
  for (int k = 0; k < 4; ++k) {
    h[k] = bf16_rtn(ff[k]);
    const float fh = __uint_as_float((unsigned)h[k] << 16);
    l[k] = bf16_rtn(ff[k] - fh);
  }
  *(ushort4*)&hi[i * 4] = make_ushort4(h[0], h[1], h[2], h[3]);
  *(ushort4*)&lo[i * 4] = make_ushort4(l[0], l[1], l[2], l[3]);
}

// ---------------------------------------------------------------------------
// K3: logits = hs @ W_fc^T + b_fc, bf16 hi/lo split MFMA (hh+hl+lh).
// m97-style staging: global_load_lds width-16 into LINEAR [128][32]-bf16
// tiles; bank spread via XOR chunk-swizzle (chunk ^= row&3) applied on the
// pre-swizzled GLOBAL source (m173 pattern) and on the ds_read side.
// 4 waves: wave w stages array w (Ah/Al/Bh/Bl), 8 instrs x 1KB per k-step.
// ---------------------------------------------------------------------------
__global__ __launch_bounds__(256) void k3_logits(
    const unsigned short* __restrict__ Ahi, const unsigned short* __restrict__ Alo,
    const unsigned short* __restrict__ Bhi, const unsigned short* __restrict__ Blo,
    const float* __restrict__ b_fc, float* __restrict__ out) {
  __shared__ unsigned short Ah[128 * 32], Al[128 * 32];
  __shared__ unsigned short Bh[128 * 32], Bl[128 * 32];
  const int m0 = blockIdx.x * 128;
  const int n0 = blockIdx.y * 128;
  const int tid = threadIdx.x;
  const int lane = tid & 63;
  const int wave = tid >> 6;
  const int wm = wave >> 1, wn = wave & 1;
  const int lr = lane & 15;
  const int cxr = ((lane >> 4) ^ (lr & 3)) * 8;  // swizzled k-chunk (shorts)

  // staging assignment: wave w owns one array
  const unsigned short* gp = (wave == 0) ? Ahi : (wave == 1) ? Alo
                           : (wave == 2) ? Bhi : Blo;
  unsigned short* lp = (wave == 0) ? Ah : (wave == 1) ? Al
                     : (wave == 2) ? Bh : Bl;
  const bool isB = wave >= 2;
  const int lrow = lane >> 2;                    // 0..15 row within chunk
  const int lchunk = (lane & 3) ^ (lrow & 3);    // pre-swizzled source chunk

  f32x4 acc[4][4];
#pragma unroll
  for (int mi = 0; mi < 4; ++mi)
#pragma unroll
    for (int ni = 0; ni < 4; ++ni) acc[mi][ni] = (f32x4)0.0f;

  for (int k0 = 0; k0 < H_; k0 += 32) {
    __syncthreads();  // previous iteration's frag reads done
#pragma unroll
    for (int c16 = 0; c16 < 8; ++c16) {
      const int r = c16 * 16 + lrow;
      const int grow = isB ? min(n0 + r, V_ - 1) : (m0 + r);
      const unsigned short* src = gp + (size_t)grow * H_ + k0 + lchunk * 8;
      __builtin_amdgcn_global_load_lds(
          (const __attribute__((address_space(1))) void*)src,
          (__attribute__((address_space(3))) void*)(lp + c16 * 512), 16, 0, 0);
    }
    __syncthreads();  // drains vmcnt(0): tiles ready

    bf16x8 ah[4], al[4], bh[4], bl[4];
#pragma unroll
    for (int i = 0; i < 4; ++i) {
      ah[i] = *(const bf16x8*)&Ah[(wm * 64 + i * 16 + lr) * 32 + cxr];
      al[i] = *(const bf16x8*)&Al[(wm * 64 + i * 16 + lr) * 32 + cxr];
      bh[i] = *(const bf16x8*)&Bh[(wn * 64 + i * 16 + lr) * 32 + cxr];
      bl[i] = *(const bf16x8*)&Bl[(wn * 64 + i * 16 + lr) * 32 + cxr];
    }
#pragma unroll
    for (int mi = 0; mi < 4; ++mi)
#pragma unroll
      for (int ni = 0; ni < 4; ++ni) {
        acc[mi][ni] = __builtin_amdgcn_mfma_f32_16x16x32_bf16(
            ah[mi], bh[ni], acc[mi][ni], 0, 0, 0);
        acc[mi][ni] = __builtin_amdgcn_mfma_f32_16x16x32_bf16(
            ah[mi], bl[ni], acc[mi][ni], 0, 0, 0);
        acc[mi][ni] = __builtin_amdgcn_mfma_f32_16x16x32_bf16(
            al[mi], bh[ni], acc[mi][ni], 0, 0, 0);
      }
  }

#pragma unroll
  for (int ni = 0; ni < 4; ++ni) {
    const int v = n0 + wn * 64 + ni * 16 + lr;
    if (v >= V_) continue;
    const float bias = b_fc[v];
#pragma unroll
    for (int mi = 0; mi < 4; ++mi) {
      const int mrow = m0 + wm * 64 + mi * 16 + (lane >> 4) * 4;
#pragma unroll
      for (int r = 0; r < 4; ++r)
        out[(size_t)(mrow + r) * V_ + v] = acc[mi][ni][r] + bias;
    }
  }
}

// ---------------------------------------------------------------------------
// K4a: per-(b,v) online max+sum over S; stores (m, 1/sum).
// ---------------------------------------------------------------------------
__global__ __launch_bounds__(256) void k4_stats(const float* __restrict__ logits,
                                                float* __restrict__ stats) {
  const int g = blockIdx.x * 256 + threadIdx.x;
  const int b = g / V_;
  const int v = g - b * V_;
  const float* p = logits + (size_t)b * S_ * V_ + v;
  float m = -3.4e38f, sum = 0.f;
  for (int s = 0; s < S_; ++s) {
    const float xv = p[(size_t)s * V_];
    if (xv > m) {
      sum = sum * __expf(m - xv) + 1.f;
      m = xv;
    } else {
      sum += __expf(xv - m);
    }
  }
  stats[2 * g] = m;
  stats[2 * g + 1] = 1.f / sum;
}

// ---------------------------------------------------------------------------
// K4b: in-place normalize: out = exp(l - m) * inv_sum
// ---------------------------------------------------------------------------
__global__ __launch_bounds__(256) void k4_norm(float* __restrict__ logits,
                                               const float* __restrict__ stats) {
  const size_t idx = (size_t)blockIdx.x * 256 + threadIdx.x;
  const int v = (int)(idx % V_);
  const int b = (int)(idx / ((size_t)S_ * V_));
  const int g = b * V_ + v;
  const float m = stats[2 * g];
  const float inv = stats[2 * g + 1];
  logits[idx] = __expf(logits[idx] - m) * inv;
}

extern "C" void kernel_launch(void* const* d_in, const int* in_sizes, int n_in,
                              void* d_out, int out_size, void* d_ws,
                              size_t ws_size, hipStream_t stream) {
  const float* x    = (const float*)d_in[0];
  const float* W_ih = (const float*)d_in[1];
  const float* W_hh = (const float*)d_in[2];
  const float* b_ih = (const float*)d_in[3];
  const float* b_hh = (const float*)d_in[4];
  const float* W_fc = (const float*)d_in[5];
  const float* b_fc = (const float*)d_in[6];
  float* out = (float*)d_out;

  // ws layout (floats): xw | hs | stats | wfc_hi | wfc_lo
  //   part (256 KB, scan-only) ALIASES wfc_hi (k2 done before k5_wfc)
  //   hs_hi/hs_lo (bf16) ALIAS xw (dead after k2)
  float* ws = (float*)d_ws;
  float* xw    = ws;
  float* hs    = xw + (size_t)BS_ * H_;
  float* stats = hs + (size_t)BS_ * H_;
  unsigned short* wfc_hi = (unsigned short*)(stats + (size_t)2 * B_ * V_);
  unsigned short* wfc_lo = wfc_hi + (size_t)V_ * H_;
  u64* part = (u64*)wfc_hi;
  unsigned short* hs_hi = (unsigned short*)xw;
  unsigned short* hs_lo = hs_hi + (size_t)BS_ * H_;

  k0_init<<<(4 * B_ * H_) / 256, 256, 0, stream>>>(part);
  k1_xw<<<dim3(BS_ / 16, H_ / 16), 256, 0, stream>>>(x, W_ih, b_ih, b_hh, xw);
  k2_scan<<<NBLK, 512, 0, stream>>>(xw, W_hh, hs, part);
  k5_split<<<((V_ * H_ / 4) + 255) / 256, 256, 0, stream>>>(W_fc, wfc_hi,
                                                            wfc_lo, V_ * H_ / 4);
  k5_split<<<((BS_ * H_ / 4) + 255) / 256, 256, 0, stream>>>(
      hs, hs_hi, hs_lo, BS_ * H_ / 4);
  k3_logits<<<dim3(BS_ / 128, (V_ + 127) / 128), 256, 0, stream>>>(
      hs_hi, hs_lo, wfc_hi, wfc_lo, b_fc, out);
  k4_stats<<<(B_ * V_) / 256, 256, 0, stream>>>(out, stats);
  k4_norm<<<(int)((size_t)BS_ * V_ / 256), 256, 0, stream>>>(out, stats);
}